// Round 4
// baseline (401.719 us; speedup 1.0000x reference)
//
#include <hip/hip_runtime.h>
#include <hip/hip_bf16.h>
#include <cstddef>

// MHA: B=2, N=4096, E=512, H=8, D=64.
// proj GEMMs (128x64 tile, fp32->bf16) -> flash attn (transposed-S, no-max
// softmax, barrier-free, 4-wave blocks sharing one head's K/V stream via L1)
// -> final proj (f32 out).
// Q projection pre-scaled by 0.125*log2(e) so S^T MFMA output is the exp2 arg.

typedef __bf16 bf16_t;
typedef __bf16 bf16x8 __attribute__((ext_vector_type(8)));
typedef __bf16 bf16x4 __attribute__((ext_vector_type(4)));
typedef float  f32x4  __attribute__((ext_vector_type(4)));

#define MFMA_BF16 __builtin_amdgcn_mfma_f32_16x16x32_bf16

// ---------------------------------------------------------------------------
// proj_gemm: C[8192 x 512] = X[8192 x 512] @ W[512 x 512]^T + bias, * scale
// Tile 128x64 (BM=128, BN=64), 256 threads; wave w -> 64x32 quadrant.
// MODE 0: bf16 out [B,H,N,D] (Q,K)   MODE 1: bf16 out [B,H,D,N] (V)
// MODE 2: f32 out  [B,N,E]   (final O-projection)
// ---------------------------------------------------------------------------
template<bool XF32, int MODE>
__global__ void __launch_bounds__(256)
proj_gemm(const void* __restrict__ Xv, const float* __restrict__ W,
          const float* __restrict__ bias, void* __restrict__ outv, float scale)
{
  // row stride 40 bf16 = 80 B (16B-aligned rows, breaks pow-2 banking)
  __shared__ __align__(16) bf16_t Xs[128 * 40];
  __shared__ __align__(16) bf16_t Ws[64 * 40];
  const int mtile = blockIdx.x;      // 0..63
  const int ntile = blockIdx.y;      // 0..7
  const int tid   = threadIdx.x;
  const int w     = tid >> 6;
  const int lane  = tid & 63;
  const int lr    = lane & 15;
  const int quad  = lane >> 4;
  const int wm    = w & 1;           // m-half (64 rows)
  const int wn    = w >> 1;          // n-half (32 cols)
  const int xrow  = tid >> 1, xkg = (tid & 1) << 4;  // X stage: 16 elems
  const int wrow  = tid >> 2, wkg = (tid & 3) << 3;  // W stage: 8 elems

  float bvv[2];
#pragma unroll
  for (int ci = 0; ci < 2; ++ci) bvv[ci] = bias[ntile * 64 + wn * 32 + ci * 16 + lr];

  f32x4 acc[4][2] = {};

  const float*  Xf = (const float*)Xv;
  const bf16_t* Xb = (const bf16_t*)Xv;

  for (int k0 = 0; k0 < 512; k0 += 32) {
    // ---- stage X tile 128x32 ----
    {
      bf16_t* dx = Xs + xrow * 40 + xkg;
      if constexpr (XF32) {
        const float* p = Xf + (size_t)(mtile * 128 + xrow) * 512 + k0 + xkg;
        float4 a = *(const float4*)p;
        float4 b = *(const float4*)(p + 4);
        float4 c = *(const float4*)(p + 8);
        float4 d = *(const float4*)(p + 12);
        bf16x8 v0 = {(bf16_t)a.x,(bf16_t)a.y,(bf16_t)a.z,(bf16_t)a.w,
                     (bf16_t)b.x,(bf16_t)b.y,(bf16_t)b.z,(bf16_t)b.w};
        bf16x8 v1 = {(bf16_t)c.x,(bf16_t)c.y,(bf16_t)c.z,(bf16_t)c.w,
                     (bf16_t)d.x,(bf16_t)d.y,(bf16_t)d.z,(bf16_t)d.w};
        *(bf16x8*)dx = v0;
        *(bf16x8*)(dx + 8) = v1;
      } else {
        const bf16_t* p = Xb + (size_t)(mtile * 128 + xrow) * 512 + k0 + xkg;
        *(bf16x8*)dx       = *(const bf16x8*)p;
        *(bf16x8*)(dx + 8) = *(const bf16x8*)(p + 8);
      }
      // ---- stage W tile 64x32 ----
      const float* pw = W + (size_t)(ntile * 64 + wrow) * 512 + k0 + wkg;
      float4 a = *(const float4*)pw;
      float4 b = *(const float4*)(pw + 4);
      bf16x8 vw = {(bf16_t)a.x,(bf16_t)a.y,(bf16_t)a.z,(bf16_t)a.w,
                   (bf16_t)b.x,(bf16_t)b.y,(bf16_t)b.z,(bf16_t)b.w};
      *(bf16x8*)(Ws + wrow * 40 + wkg) = vw;
    }
    __syncthreads();
    bf16x8 af[4], bfr[2];
#pragma unroll
    for (int mi = 0; mi < 4; ++mi)
      af[mi] = *(const bf16x8*)(Xs + (wm * 64 + mi * 16 + lr) * 40 + quad * 8);
#pragma unroll
    for (int ci = 0; ci < 2; ++ci)
      bfr[ci] = *(const bf16x8*)(Ws + (wn * 32 + ci * 16 + lr) * 40 + quad * 8);
#pragma unroll
    for (int mi = 0; mi < 4; ++mi)
#pragma unroll
      for (int ci = 0; ci < 2; ++ci)
        acc[mi][ci] = MFMA_BF16(af[mi], bfr[ci], acc[mi][ci], 0, 0, 0);
    __syncthreads();
  }

  // C/D layout: col = lane&15 (n), row = quad*4 + reg (m)
#pragma unroll
  for (int mi = 0; mi < 4; ++mi) {
    const int gm0 = mtile * 128 + wm * 64 + mi * 16 + quad * 4;
#pragma unroll
    for (int ci = 0; ci < 2; ++ci) {
      const int gc = ntile * 64 + wn * 32 + ci * 16 + lr;
      if constexpr (MODE == 0) {
        bf16_t* out = (bf16_t*)outv;
        const int h = gc >> 6, dd = gc & 63;
#pragma unroll
        for (int r = 0; r < 4; ++r) {
          const int gm = gm0 + r;
          const int b = gm >> 12, n = gm & 4095;
          out[(size_t)((b * 8 + h) * 4096 + n) * 64 + dd] =
              (bf16_t)((acc[mi][ci][r] + bvv[ci]) * scale);
        }
      } else if constexpr (MODE == 1) {
        bf16_t* out = (bf16_t*)outv;
        const int h = gc >> 6, dd = gc & 63;
        const int b = gm0 >> 12, n0 = gm0 & 4095;  // 4 consecutive n, same b
        bf16x4 pk;
#pragma unroll
        for (int r = 0; r < 4; ++r) pk[r] = (bf16_t)(acc[mi][ci][r] + bvv[ci]);
        *(bf16x4*)(out + (size_t)((b * 8 + h) * 64 + dd) * 4096 + n0) = pk;
      } else {
        float* out = (float*)outv;
#pragma unroll
        for (int r = 0; r < 4; ++r)
          out[(size_t)(gm0 + r) * 512 + gc] = acc[mi][ci][r] + bvv[ci];
      }
    }
  }
}

// ---------------------------------------------------------------------------
// flash_attn v4: 256-thread blocks = 4 INDEPENDENT waves (no barriers), each
// wave owns 32 q-rows; all 4 waves + same-CU blocks share one head's K/V
// stream (grid x = head) so redundant fragment loads hit L1 and the per-XCD
// working set (~2 heads = 4 MB) fits L2. Transposed S (S^T = K @ Q^T), fixed
// m=0 softmax (Q pre-scaled), per-wave LDS P-transpose, 1-chunk register
// prefetch pipeline.
// ---------------------------------------------------------------------------
__global__ void __launch_bounds__(256)
flash_attn(const bf16_t* __restrict__ Qp, const bf16_t* __restrict__ Kp,
           const bf16_t* __restrict__ Vt, bf16_t* __restrict__ Oc)
{
  __shared__ __align__(16) bf16_t P2[4][2][32 * 40];  // per-wave double buffer
  const int w    = threadIdx.x >> 6;        // wave 0..3
  const int lane = threadIdx.x & 63, lr = lane & 15, quad = lane >> 4;
  const int bh   = blockIdx.x;              // 0..15  (same-CU blocks share bh)
  const int qt   = blockIdx.y * 4 + w;      // 0..127 (32 q-rows per wave)

  const bf16_t* Qh = Qp + (size_t)bh * 4096 * 64;
  const bf16_t* Kh = Kp + (size_t)bh * 4096 * 64;
  const bf16_t* Vh = Vt + (size_t)bh * 64 * 4096;

  // Q B-frags for S^T: B[k=d][n=q], lane holds q=lr, d=kh*32+quad*8+j
  bf16x8 qf[2][2];
#pragma unroll
  for (int qi = 0; qi < 2; ++qi)
#pragma unroll
    for (int kh = 0; kh < 2; ++kh)
      qf[qi][kh] = *(const bf16x8*)(Qh + (size_t)(qt * 32 + qi * 16 + lr) * 64 + kh * 32 + quad * 8);

  f32x4 acc[2][4] = {};   // O C-layout: [qi][d-tile t]; row=q(quad*4+r), col=d(lr)
  float lsum[2] = {0.f, 0.f};  // per-lane partial row-sum, q = qi*16+lr
  const f32x4 zero = {0.f, 0.f, 0.f, 0.f};

  // double-buffered K/V fragments (software pipeline, 1 chunk ahead)
  bf16x8 kf[2][2][2];  // [buf][kv-tile mt][d-half kh]; A[m=kv][k=d]
  bf16x8 vf[2][4];     // [buf][d-tile t];              B[k=kv][n=d]

#pragma unroll
  for (int mt = 0; mt < 2; ++mt)
#pragma unroll
    for (int kh = 0; kh < 2; ++kh)
      kf[0][mt][kh] = *(const bf16x8*)(Kh + (size_t)(mt * 16 + lr) * 64 + kh * 32 + quad * 8);
#pragma unroll
  for (int t = 0; t < 4; ++t)
    vf[0][t] = *(const bf16x8*)(Vh + (size_t)(t * 16 + lr) * 4096 + quad * 8);

#pragma unroll 2
  for (int it = 0; it < 128; ++it) {
    const int cur = it & 1, nxt = cur ^ 1;
    const int kv0 = it << 5;
    const int kvn = (kv0 + 32) & 4095;  // last iter wraps to 0 (harmless)
    bf16_t* Pw = &P2[w][cur][0];

    // ---- issue next chunk's loads (latency hidden by compute below) ----
#pragma unroll
    for (int mt = 0; mt < 2; ++mt)
#pragma unroll
      for (int kh = 0; kh < 2; ++kh)
        kf[nxt][mt][kh] = *(const bf16x8*)(Kh + (size_t)(kvn + mt * 16 + lr) * 64 + kh * 32 + quad * 8);
#pragma unroll
    for (int t = 0; t < 4; ++t)
      vf[nxt][t] = *(const bf16x8*)(Vh + (size_t)(t * 16 + lr) * 4096 + kvn + quad * 8);

    // ---- S^T tiles: D[m=kv][n=q] ----
    f32x4 sT[2][2];
#pragma unroll
    for (int mt = 0; mt < 2; ++mt)
#pragma unroll
      for (int qi = 0; qi < 2; ++qi) {
        sT[mt][qi] = MFMA_BF16(kf[cur][mt][0], qf[qi][0], zero, 0, 0, 0);
        sT[mt][qi] = MFMA_BF16(kf[cur][mt][1], qf[qi][1], sT[mt][qi], 0, 0, 0);
      }

    // ---- p = exp2(sT); transpose P^T(C-layout) -> P(A-layout) via LDS ----
#pragma unroll
    for (int mt = 0; mt < 2; ++mt)
#pragma unroll
      for (int qi = 0; qi < 2; ++qi) {
        float p0 = __builtin_amdgcn_exp2f(sT[mt][qi][0]);
        float p1 = __builtin_amdgcn_exp2f(sT[mt][qi][1]);
        float p2 = __builtin_amdgcn_exp2f(sT[mt][qi][2]);
        float p3 = __builtin_amdgcn_exp2f(sT[mt][qi][3]);
        lsum[qi] += (p0 + p1) + (p2 + p3);
        bf16x4 pk = {(bf16_t)p0, (bf16_t)p1, (bf16_t)p2, (bf16_t)p3};
        *(bf16x4*)(Pw + (qi * 16 + lr) * 40 + mt * 16 + quad * 4) = pk;
      }

    // ---- P A-frags: A[m=q][k=kv=quad*8+j] (wave-private: no barrier) ----
    bf16x8 pa[2];
#pragma unroll
    for (int qi = 0; qi < 2; ++qi)
      pa[qi] = *(const bf16x8*)(Pw + (qi * 16 + lr) * 40 + quad * 8);

    // ---- O += P @ V ----
#pragma unroll
    for (int t = 0; t < 4; ++t) {
      acc[0][t] = MFMA_BF16(pa[0], vf[cur][t], acc[0][t], 0, 0, 0);
      acc[1][t] = MFMA_BF16(pa[1], vf[cur][t], acc[1][t], 0, 0, 0);
    }
  }

  // reduce lsum over the 4 quads (lanes differing in bits 4,5; same lr)
#pragma unroll
  for (int qi = 0; qi < 2; ++qi) {
    lsum[qi] += __shfl_xor(lsum[qi], 16);
    lsum[qi] += __shfl_xor(lsum[qi], 32);
  }

  const int b = bh >> 3, h = bh & 7;
  bf16_t* Ob = Oc + (size_t)b * 4096 * 512 + h * 64;
#pragma unroll
  for (int qi = 0; qi < 2; ++qi) {
    float inv[4];
#pragma unroll
    for (int r = 0; r < 4; ++r)
      inv[r] = 1.0f / __shfl(lsum[qi], quad * 4 + r);  // lsum lives at lane lr=q
#pragma unroll
    for (int t = 0; t < 4; ++t)
#pragma unroll
      for (int r = 0; r < 4; ++r) {
        const int n = qt * 32 + qi * 16 + quad * 4 + r;
        Ob[(size_t)n * 512 + t * 16 + lr] = (bf16_t)(acc[qi][t][r] * inv[r]);
      }
  }
}

// ---------------------------------------------------------------------------
extern "C" void kernel_launch(void* const* d_in, const int* in_sizes, int n_in,
                              void* d_out, int out_size, void* d_ws, size_t ws_size,
                              hipStream_t stream)
{
  const float* q  = (const float*)d_in[0];
  const float* k  = (const float*)d_in[1];
  const float* v  = (const float*)d_in[2];
  const float* Wq = (const float*)d_in[3];
  const float* bq = (const float*)d_in[4];
  const float* Wk = (const float*)d_in[5];
  const float* bk = (const float*)d_in[6];
  const float* Wv = (const float*)d_in[7];
  const float* bv = (const float*)d_in[8];
  const float* Wo = (const float*)d_in[9];
  const float* bo = (const float*)d_in[10];

  const size_t HEAD_ELEMS = (size_t)2 * 8 * 4096 * 64;  // 8 MB bf16 each
  bf16_t* Qp = (bf16_t*)d_ws;          // [B,H,N,D], pre-scaled
  bf16_t* Kp = Qp + HEAD_ELEMS;        // [B,H,N,D]
  bf16_t* Vt = Kp + HEAD_ELEMS;        // [B,H,D,N]
  bf16_t* Oc = Vt + HEAD_ELEMS;        // [B,N,E]

  const float qscale = 0.125f * 1.44269504f;  // 1/sqrt(D) * log2(e)

  dim3 gp(64, 8);
  proj_gemm<true, 0><<<gp, 256, 0, stream>>>((const void*)q, Wq, bq, (void*)Qp, qscale);
  proj_gemm<true, 0><<<gp, 256, 0, stream>>>((const void*)k, Wk, bk, (void*)Kp, 1.0f);
  proj_gemm<true, 1><<<gp, 256, 0, stream>>>((const void*)v, Wv, bv, (void*)Vt, 1.0f);
  flash_attn<<<dim3(16, 32), 256, 0, stream>>>(Qp, Kp, Vt, Oc);
  proj_gemm<false, 2><<<gp, 256, 0, stream>>>((const void*)Oc, Wo, bo, d_out, 1.0f);
}

// Round 5
// 277.113 us; speedup vs baseline: 1.4497x; 1.4497x over previous
//
#include <hip/hip_runtime.h>
#include <hip/hip_bf16.h>
#include <cstddef>
#include <cstdint>

// MHA: B=2, N=4096, E=512, H=8, D=64.
// proj GEMMs (128x64 tile, fp32->bf16) -> flash attn v5 (m97-style: KV chunks
// staged to double-buffered LDS via async global_load_lds, 128-q blocks,
// KC=64, no-max softmax, Q pre-scaled by 0.125*log2e) -> final proj (f32 out).

typedef __bf16 bf16_t;
typedef __bf16 bf16x8 __attribute__((ext_vector_type(8)));
typedef __bf16 bf16x4 __attribute__((ext_vector_type(4)));
typedef float  f32x4  __attribute__((ext_vector_type(4)));

#define MFMA_BF16 __builtin_amdgcn_mfma_f32_16x16x32_bf16

// async global->LDS, 16B per lane. LDS dest = wave-uniform base + lane*16.
#define GLD_LDS16(gptr, lptr)                                                  \
  __builtin_amdgcn_global_load_lds(                                            \
      (const __attribute__((address_space(1))) void*)(gptr),                   \
      (__attribute__((address_space(3))) void*)(lptr), 16, 0, 0)

// ---------------------------------------------------------------------------
// proj_gemm: C[8192 x 512] = X[8192 x 512] @ W[512 x 512]^T + bias, * scale
// Tile 128x64 (BM=128, BN=64), 256 threads; wave w -> 64x32 quadrant.
// MODE 0: bf16 out [B,H,N,D] (Q,K)   MODE 1: bf16 out [B,H,D,N] (V)
// MODE 2: f32 out  [B,N,E]   (final O-projection)
// ---------------------------------------------------------------------------
template<bool XF32, int MODE>
__global__ void __launch_bounds__(256)
proj_gemm(const void* __restrict__ Xv, const float* __restrict__ W,
          const float* __restrict__ bias, void* __restrict__ outv, float scale)
{
  __shared__ __align__(16) bf16_t Xs[128 * 40];
  __shared__ __align__(16) bf16_t Ws[64 * 40];
  const int mtile = blockIdx.x;      // 0..63
  const int ntile = blockIdx.y;      // 0..7
  const int tid   = threadIdx.x;
  const int w     = tid >> 6;
  const int lane  = tid & 63;
  const int lr    = lane & 15;
  const int quad  = lane >> 4;
  const int wm    = w & 1;           // m-half (64 rows)
  const int wn    = w >> 1;          // n-half (32 cols)
  const int xrow  = tid >> 1, xkg = (tid & 1) << 4;  // X stage: 16 elems
  const int wrow  = tid >> 2, wkg = (tid & 3) << 3;  // W stage: 8 elems

  float bvv[2];
#pragma unroll
  for (int ci = 0; ci < 2; ++ci) bvv[ci] = bias[ntile * 64 + wn * 32 + ci * 16 + lr];

  f32x4 acc[4][2] = {};

  const float*  Xf = (const float*)Xv;
  const bf16_t* Xb = (const bf16_t*)Xv;

  for (int k0 = 0; k0 < 512; k0 += 32) {
    {
      bf16_t* dx = Xs + xrow * 40 + xkg;
      if constexpr (XF32) {
        const float* p = Xf + (size_t)(mtile * 128 + xrow) * 512 + k0 + xkg;
        float4 a = *(const float4*)p;
        float4 b = *(const float4*)(p + 4);
        float4 c = *(const float4*)(p + 8);
        float4 d = *(const float4*)(p + 12);
        bf16x8 v0 = {(bf16_t)a.x,(bf16_t)a.y,(bf16_t)a.z,(bf16_t)a.w,
                     (bf16_t)b.x,(bf16_t)b.y,(bf16_t)b.z,(bf16_t)b.w};
        bf16x8 v1 = {(bf16_t)c.x,(bf16_t)c.y,(bf16_t)c.z,(bf16_t)c.w,
                     (bf16_t)d.x,(bf16_t)d.y,(bf16_t)d.z,(bf16_t)d.w};
        *(bf16x8*)dx = v0;
        *(bf16x8*)(dx + 8) = v1;
      } else {
        const bf16_t* p = Xb + (size_t)(mtile * 128 + xrow) * 512 + k0 + xkg;
        *(bf16x8*)dx       = *(const bf16x8*)p;
        *(bf16x8*)(dx + 8) = *(const bf16x8*)(p + 8);
      }
      const float* pw = W + (size_t)(ntile * 64 + wrow) * 512 + k0 + wkg;
      float4 a = *(const float4*)pw;
      float4 b = *(const float4*)(pw + 4);
      bf16x8 vw = {(bf16_t)a.x,(bf16_t)a.y,(bf16_t)a.z,(bf16_t)a.w,
                   (bf16_t)b.x,(bf16_t)b.y,(bf16_t)b.z,(bf16_t)b.w};
      *(bf16x8*)(Ws + wrow * 40 + wkg) = vw;
    }
    __syncthreads();
    bf16x8 af[4], bfr[2];
#pragma unroll
    for (int mi = 0; mi < 4; ++mi)
      af[mi] = *(const bf16x8*)(Xs + (wm * 64 + mi * 16 + lr) * 40 + quad * 8);
#pragma unroll
    for (int ci = 0; ci < 2; ++ci)
      bfr[ci] = *(const bf16x8*)(Ws + (wn * 32 + ci * 16 + lr) * 40 + quad * 8);
#pragma unroll
    for (int mi = 0; mi < 4; ++mi)
#pragma unroll
      for (int ci = 0; ci < 2; ++ci)
        acc[mi][ci] = MFMA_BF16(af[mi], bfr[ci], acc[mi][ci], 0, 0, 0);
    __syncthreads();
  }

  // C/D layout: col = lane&15 (n), row = quad*4 + reg (m)
#pragma unroll
  for (int mi = 0; mi < 4; ++mi) {
    const int gm0 = mtile * 128 + wm * 64 + mi * 16 + quad * 4;
#pragma unroll
    for (int ci = 0; ci < 2; ++ci) {
      const int gc = ntile * 64 + wn * 32 + ci * 16 + lr;
      if constexpr (MODE == 0) {
        bf16_t* out = (bf16_t*)outv;
        const int h = gc >> 6, dd = gc & 63;
#pragma unroll
        for (int r = 0; r < 4; ++r) {
          const int gm = gm0 + r;
          const int b = gm >> 12, n = gm & 4095;
          out[(size_t)((b * 8 + h) * 4096 + n) * 64 + dd] =
              (bf16_t)((acc[mi][ci][r] + bvv[ci]) * scale);
        }
      } else if constexpr (MODE == 1) {
        bf16_t* out = (bf16_t*)outv;
        const int h = gc >> 6, dd = gc & 63;
        const int b = gm0 >> 12, n0 = gm0 & 4095;  // 4 consecutive n, same b
        bf16x4 pk;
#pragma unroll
        for (int r = 0; r < 4; ++r) pk[r] = (bf16_t)(acc[mi][ci][r] + bvv[ci]);
        *(bf16x4*)(out + (size_t)((b * 8 + h) * 64 + dd) * 4096 + n0) = pk;
      } else {
        float* out = (float*)outv;
#pragma unroll
        for (int r = 0; r < 4; ++r)
          out[(size_t)(gm0 + r) * 512 + gc] = acc[mi][ci][r] + bvv[ci];
      }
    }
  }
}

// ---------------------------------------------------------------------------
// flash_attn v5 (m97-style): block = 256 thr (4 waves), 128 q-rows per block
// (32 per wave), one head per block. KV chunk KC=64 staged cooperatively into
// double-buffered LDS via async global_load_lds (width 16): chunk i+1 issued
// at the top of iter i, drained by the end-of-iter __syncthreads after ~1.5k
// cycles of compute. Transposed S (S^T = K @ Q^T), fixed m=0 softmax (Q
// pre-scaled), wave-private padded P buffer for the C->A transpose.
// ---------------------------------------------------------------------------
__global__ void __launch_bounds__(256, 2)
flash_attn(const bf16_t* __restrict__ Qp, const bf16_t* __restrict__ Kp,
           const bf16_t* __restrict__ Vt, bf16_t* __restrict__ Oc)
{
  __shared__ __align__(16) bf16_t Klds[2][64 * 64];  // [kv][d]   8 KB each
  __shared__ __align__(16) bf16_t Vlds[2][64 * 64];  // [d][kv]   8 KB each
  __shared__ __align__(16) bf16_t Pl[4][32 * 72];    // per-wave, padded

  const int tid  = threadIdx.x;
  const int w    = tid >> 6;                 // wave 0..3
  const int lane = tid & 63, lr = lane & 15, quad = lane >> 4;
  const int bh   = blockIdx.x;               // 0..15
  const int qt   = blockIdx.y * 4 + w;       // 0..127 (32 q-rows per wave)

  const bf16_t* Qh = Qp + (size_t)bh * 4096 * 64;
  const bf16_t* Kh = Kp + (size_t)bh * 4096 * 64;
  const bf16_t* Vh = Vt + (size_t)bh * 64 * 4096;

  // ---- staging address precompute (2 K-insts + 2 V-insts per wave) ----
  // segment s = w*2+j covers LDS bytes [s*1024, s*1024+1024)
  const int seg0 = w << 1;
  // V gather: lane's byte L = s*1024 + lane*16 -> d-row = s*8 + lane/8,
  // col byte = (lane&7)*16
  const int vdrow_l = lane >> 3;             // + s*8
  const int vcolb   = (lane & 7) << 4;

  // Q B-frags for S^T: B[k=d][n=q], lane holds q=lr, d=kh*32+quad*8+j
  bf16x8 qf[2][2];
#pragma unroll
  for (int qi = 0; qi < 2; ++qi)
#pragma unroll
    for (int kh = 0; kh < 2; ++kh)
      qf[qi][kh] = *(const bf16x8*)(Qh + (size_t)(qt * 32 + qi * 16 + lr) * 64 + kh * 32 + quad * 8);

  // ---- prologue: stage chunk 0 into buffer 0 ----
#pragma unroll
  for (int j = 0; j < 2; ++j) {
    const int s = seg0 + j;
    GLD_LDS16(Kh + s * 512 + lane * 8, (bf16_t*)&Klds[0][0] + s * 512);
    GLD_LDS16((const char*)Vh + (size_t)(s * 8 + vdrow_l) * 8192 + vcolb,
              (bf16_t*)&Vlds[0][0] + s * 512);
  }
  __syncthreads();

  f32x4 acc[2][4] = {};        // O C-layout: [qi][d-tile t]
  float lsum[2] = {0.f, 0.f};  // per-lane partial row-sum, q = qi*16+lr
  const f32x4 zero = {0.f, 0.f, 0.f, 0.f};
  bf16_t* Pw = &Pl[w][0];

  for (int it = 0; it < 64; ++it) {
    const int cur = it & 1, nxt = cur ^ 1;

    // ---- fire-and-forget stage of chunk it+1 (drained at the barrier) ----
    if (it != 63) {
      const int kvn = (it + 1) << 6;
#pragma unroll
      for (int j = 0; j < 2; ++j) {
        const int s = seg0 + j;
        GLD_LDS16(Kh + (size_t)kvn * 64 + s * 512 + lane * 8,
                  (bf16_t*)&Klds[nxt][0] + s * 512);
        GLD_LDS16((const char*)Vh + (size_t)(s * 8 + vdrow_l) * 8192 + (size_t)kvn * 2 + vcolb,
                  (bf16_t*)&Vlds[nxt][0] + s * 512);
      }
    }

    // ---- K/V fragments from LDS ----
    bf16x8 kf[4][2];  // A[m=kv=mt*16+lr][k=d=kh*32+quad*8+j]
#pragma unroll
    for (int mt = 0; mt < 4; ++mt)
#pragma unroll
      for (int kh = 0; kh < 2; ++kh)
        kf[mt][kh] = *(const bf16x8*)(&Klds[cur][(mt * 16 + lr) * 64 + kh * 32 + quad * 8]);
    bf16x8 vf[4][2];  // B[k=kv=kvh*32+quad*8+j][n=d=t*16+lr]
#pragma unroll
    for (int t = 0; t < 4; ++t)
#pragma unroll
      for (int kvh = 0; kvh < 2; ++kvh)
        vf[t][kvh] = *(const bf16x8*)(&Vlds[cur][(t * 16 + lr) * 64 + kvh * 32 + quad * 8]);

    // ---- S^T = K @ Q^T : D[m=kv][n=q], 16 MFMAs ----
    f32x4 sT[4][2];
#pragma unroll
    for (int mt = 0; mt < 4; ++mt)
#pragma unroll
      for (int qi = 0; qi < 2; ++qi) {
        sT[mt][qi] = MFMA_BF16(kf[mt][0], qf[qi][0], zero, 0, 0, 0);
        sT[mt][qi] = MFMA_BF16(kf[mt][1], qf[qi][1], sT[mt][qi], 0, 0, 0);
      }

    // ---- p = exp2(sT); transpose P^T(C-layout) -> P(A-layout) via LDS ----
#pragma unroll
    for (int mt = 0; mt < 4; ++mt)
#pragma unroll
      for (int qi = 0; qi < 2; ++qi) {
        float p0 = __builtin_amdgcn_exp2f(sT[mt][qi][0]);
        float p1 = __builtin_amdgcn_exp2f(sT[mt][qi][1]);
        float p2 = __builtin_amdgcn_exp2f(sT[mt][qi][2]);
        float p3 = __builtin_amdgcn_exp2f(sT[mt][qi][3]);
        lsum[qi] += (p0 + p1) + (p2 + p3);
        bf16x4 pk = {(bf16_t)p0, (bf16_t)p1, (bf16_t)p2, (bf16_t)p3};
        *(bf16x4*)(Pw + (qi * 16 + lr) * 72 + mt * 16 + quad * 4) = pk;
      }

    // ---- P A-frags (wave-private buffer: lgkmcnt only, no barrier) ----
    bf16x8 pa[2][2];  // [qi][kvh]
#pragma unroll
    for (int qi = 0; qi < 2; ++qi)
#pragma unroll
      for (int kvh = 0; kvh < 2; ++kvh)
        pa[qi][kvh] = *(const bf16x8*)(Pw + (qi * 16 + lr) * 72 + kvh * 32 + quad * 8);

    // ---- O += P @ V : 16 MFMAs ----
#pragma unroll
    for (int t = 0; t < 4; ++t)
#pragma unroll
      for (int qi = 0; qi < 2; ++qi) {
        acc[qi][t] = MFMA_BF16(pa[qi][0], vf[t][0], acc[qi][t], 0, 0, 0);
        acc[qi][t] = MFMA_BF16(pa[qi][1], vf[t][1], acc[qi][t], 0, 0, 0);
      }

    // barrier: all waves done reading buf[cur]; also drains this wave's
    // global_load_lds for buf[nxt] (issued ~1.5k cycles ago -> cheap).
    __syncthreads();
  }

  // reduce lsum over the 4 quads (lanes differing in bits 4,5; same lr)
#pragma unroll
  for (int qi = 0; qi < 2; ++qi) {
    lsum[qi] += __shfl_xor(lsum[qi], 16);
    lsum[qi] += __shfl_xor(lsum[qi], 32);
  }

  const int b = bh >> 3, h = bh & 7;
  bf16_t* Ob = Oc + (size_t)b * 4096 * 512 + h * 64;
#pragma unroll
  for (int qi = 0; qi < 2; ++qi) {
    float inv[4];
#pragma unroll
    for (int r = 0; r < 4; ++r)
      inv[r] = 1.0f / __shfl(lsum[qi], quad * 4 + r);  // lsum lives at lane lr=q
#pragma unroll
    for (int t = 0; t < 4; ++t)
#pragma unroll
      for (int r = 0; r < 4; ++r) {
        const int n = qt * 32 + qi * 16 + quad * 4 + r;
        Ob[(size_t)n * 512 + t * 16 + lr] = (bf16_t)(acc[qi][t][r] * inv[r]);
      }
  }
}

// ---------------------------------------------------------------------------
extern "C" void kernel_launch(void* const* d_in, const int* in_sizes, int n_in,
                              void* d_out, int out_size, void* d_ws, size_t ws_size,
                              hipStream_t stream)
{
  const float* q  = (const float*)d_in[0];
  const float* k  = (const float*)d_in[1];
  const float* v  = (const float*)d_in[2];
  const float* Wq = (const float*)d_in[3];
  const float* bq = (const float*)d_in[4];
  const float* Wk = (const float*)d_in[5];
  const float* bk = (const float*)d_in[6];
  const float* Wv = (const float*)d_in[7];
  const float* bv = (const float*)d_in[8];
  const float* Wo = (const float*)d_in[9];
  const float* bo = (const float*)d_in[10];

  const size_t HEAD_ELEMS = (size_t)2 * 8 * 4096 * 64;  // 8 MB bf16 each
  bf16_t* Qp = (bf16_t*)d_ws;          // [B,H,N,D], pre-scaled
  bf16_t* Kp = Qp + HEAD_ELEMS;        // [B,H,N,D]
  bf16_t* Vt = Kp + HEAD_ELEMS;        // [B,H,D,N]
  bf16_t* Oc = Vt + HEAD_ELEMS;        // [B,N,E]

  const float qscale = 0.125f * 1.44269504f;  // 1/sqrt(D) * log2(e)

  dim3 gp(64, 8);
  proj_gemm<true, 0><<<gp, 256, 0, stream>>>((const void*)q, Wq, bq, (void*)Qp, qscale);
  proj_gemm<true, 0><<<gp, 256, 0, stream>>>((const void*)k, Wk, bk, (void*)Kp, 1.0f);
  proj_gemm<true, 1><<<gp, 256, 0, stream>>>((const void*)v, Wv, bv, (void*)Vt, 1.0f);
  flash_attn<<<dim3(16, 32), 256, 0, stream>>>(Qp, Kp, Vt, Oc);
  proj_gemm<false, 2><<<gp, 256, 0, stream>>>((const void*)Oc, Wo, bo, d_out, 1.0f);
}